// Round 1
// baseline (511.024 us; speedup 1.0000x reference)
//
#include <hip/hip_runtime.h>
#include <hip/hip_bf16.h>
#include <math.h>

// Shapes: B=128, C=200, A=312 (pad 320), D=2048, H=1600 (pad 1664), M=B*C=25600
#define BB 128
#define CC 200
#define AA 312
#define AAP 320
#define DD 2048
#define HH 1600
#define HHP 1664
#define MM 25600

typedef __attribute__((ext_vector_type(8))) short bf16x8;
typedef __attribute__((ext_vector_type(4))) float f32x4;

__device__ __forceinline__ unsigned short f2bf(float f) {
  union { float f; unsigned int u; } v; v.f = f;
  unsigned int u = v.u;
  unsigned int r = (u + 0x7fffu + ((u >> 16) & 1u)) >> 16;
  return (unsigned short)r;
}

__device__ __forceinline__ void gload_lds16(const void* g, void* l) {
  __builtin_amdgcn_global_load_lds(
      (const __attribute__((address_space(1))) unsigned int*)g,
      (__attribute__((address_space(3))) unsigned int*)l, 16, 0, 0);
}

// ---------------- kernel 1: row l2norm of x_in -> xf (fp32) ----------------
__global__ void k_norm(const float* __restrict__ x_in, float* __restrict__ xf) {
  int b = blockIdx.x;
  int t = threadIdx.x;
  const float4* xi = (const float4*)(x_in + (size_t)b * DD);
  float4* xo = (float4*)(xf + (size_t)b * DD);
  float4 v0 = xi[t], v1 = xi[t + 256];
  float s = v0.x*v0.x + v0.y*v0.y + v0.z*v0.z + v0.w*v0.w
          + v1.x*v1.x + v1.y*v1.y + v1.z*v1.z + v1.w*v1.w;
  for (int off = 32; off; off >>= 1) s += __shfl_xor(s, off, 64);
  __shared__ float wsum[4];
  if ((t & 63) == 0) wsum[t >> 6] = s;
  __syncthreads();
  float tot = wsum[0] + wsum[1] + wsum[2] + wsum[3];
  float sc = 1.f / fmaxf(sqrtf(tot), 1e-12f);
  v0.x *= sc; v0.y *= sc; v0.z *= sc; v0.w *= sc;
  v1.x *= sc; v1.y *= sc; v1.z *= sc; v1.w *= sc;
  xo[t] = v0; xo[t + 256] = v1;
}

// ---------------- kernel 2: att = 1 + softmax(relu(xf@Wg^T+bg)/5) ----------
__global__ void k_attn(const float* __restrict__ xf, const float* __restrict__ Wg,
                       const float* __restrict__ bg, float* __restrict__ attp) {
  int b = blockIdx.x;
  int t = threadIdx.x, wv = t >> 6, ln = t & 63;
  __shared__ float xs[DD];
  __shared__ float sa[AA];
  for (int i = t; i < DD / 4; i += 256)
    ((float4*)xs)[i] = ((const float4*)(xf + (size_t)b * DD))[i];
  __syncthreads();
  for (int a = wv; a < AA; a += 4) {
    const float4* wrow = (const float4*)(Wg + (size_t)a * DD);
    float acc = 0.f;
#pragma unroll
    for (int j = 0; j < 8; j++) {
      float4 w = wrow[j * 64 + ln];
      float4 xv = ((const float4*)xs)[j * 64 + ln];
      acc += w.x * xv.x + w.y * xv.y + w.z * xv.z + w.w * xv.w;
    }
    for (int off = 32; off; off >>= 1) acc += __shfl_xor(acc, off, 64);
    if (ln == 0) sa[a] = fmaxf(acc + bg[a], 0.f) * 0.2f;  // /TMP, TMP=5
  }
  __syncthreads();
  if (wv == 0) {
    float mx = -1e30f;
    for (int i = ln; i < AA; i += 64) mx = fmaxf(mx, sa[i]);
    for (int off = 32; off; off >>= 1) mx = fmaxf(mx, __shfl_xor(mx, off, 64));
    float ev[5]; float sm = 0.f;
#pragma unroll
    for (int k = 0; k < 5; k++) {
      int i = ln + k * 64;
      ev[k] = (i < AA) ? expf(sa[i] - mx) : 0.f;
      sm += ev[k];
    }
    for (int off = 32; off; off >>= 1) sm += __shfl_xor(sm, off, 64);
    float inv = 1.f / sm;
#pragma unroll
    for (int k = 0; k < 5; k++) {
      int i = ln + k * 64;
      if (i < AA) attp[(size_t)b * AA + i] = 1.f + ev[k] * inv;
    }
  }
}

// ---------------- kernel 3: comb[m][a] = att'[b][a]*AttM[c][a] (bf16, K-pad) -
__global__ void k_comb(const float* __restrict__ attp, const float* __restrict__ AttM,
                       unsigned short* __restrict__ comb) {
  int m = blockIdx.x;
  int a = threadIdx.x;
  int b = m / CC, c = m % CC;
  unsigned short v = 0;
  if (a < AA) v = f2bf(attp[(size_t)b * AA + a] * AttM[(size_t)c * AA + a]);
  comb[(size_t)m * AAP + a] = v;
}

// ---------------- weight casts (padded, zero-filled) ------------------------
__global__ void k_cast_w1(const float* __restrict__ W1, unsigned short* __restrict__ W1b) {
  int i = blockIdx.x * 256 + threadIdx.x;
  if (i >= HHP * AAP) return;
  int r = i / AAP, c = i % AAP;
  W1b[i] = (r < HH && c < AA) ? f2bf(W1[(size_t)r * AA + c]) : (unsigned short)0;
}
__global__ void k_cast_w2(const float* __restrict__ W2, unsigned short* __restrict__ W2b) {
  int i = blockIdx.x * 256 + threadIdx.x;
  if (i >= DD * HHP) return;
  int r = i / HHP, c = i % HHP;
  W2b[i] = (c < HH) ? f2bf(W2[(size_t)r * HH + c]) : (unsigned short)0;
}

// ---------------- GEMM core macro bits (m97-style, 128x128x32, 4 waves) -----
// A row-major [M,K] bf16, B row-major [N,K] bf16 (B^T gemm). 256 threads.

// GEMM A: h = relu(comb @ W1b^T + b1) -> bf16 [MM, HHP]
__global__ __launch_bounds__(256)
void k_gemm_h(const unsigned short* __restrict__ A, const unsigned short* __restrict__ Bm,
              const float* __restrict__ bias, unsigned short* __restrict__ C) {
  const int K = AAP;
  __shared__ short As[128 * 32];
  __shared__ short Bs[128 * 32];
  int tid = threadIdx.x, wv = tid >> 6, ln = tid & 63;
  int bx = blockIdx.x, by = blockIdx.y;
  int wrow = (wv >> 1) * 64, wcol = (wv & 1) * 64;
  f32x4 acc[4][4] = {};
  size_t ar0 = (size_t)by * 128, br0 = (size_t)bx * 128;
  int soff0 = wv * 1024, soff1 = 4096 + wv * 1024;  // byte offsets of wave's chunks
  int r0 = soff0 >> 6, r1 = soff1 >> 6;             // tile rows (64B per row)
  int rl = ln >> 2;                                  // lane row within 16-row chunk
  int cbyte = (ln & 3) * 16;                         // byte col within 64B row
  for (int kt = 0; kt < K; kt += 32) {
    const char* gA0 = (const char*)(A + (ar0 + r0 + rl) * K + kt) + cbyte;
    const char* gA1 = (const char*)(A + (ar0 + r1 + rl) * K + kt) + cbyte;
    const char* gB0 = (const char*)(Bm + (br0 + r0 + rl) * K + kt) + cbyte;
    const char* gB1 = (const char*)(Bm + (br0 + r1 + rl) * K + kt) + cbyte;
    gload_lds16(gA0, &As[soff0 >> 1]);
    gload_lds16(gA1, &As[soff1 >> 1]);
    gload_lds16(gB0, &Bs[soff0 >> 1]);
    gload_lds16(gB1, &Bs[soff1 >> 1]);
    __syncthreads();
    bf16x8 af[4], bfr[4];
#pragma unroll
    for (int i = 0; i < 4; i++)
      af[i] = *(const bf16x8*)&As[(wrow + i * 16 + (ln & 15)) * 32 + (ln >> 4) * 8];
#pragma unroll
    for (int i = 0; i < 4; i++)
      bfr[i] = *(const bf16x8*)&Bs[(wcol + i * 16 + (ln & 15)) * 32 + (ln >> 4) * 8];
#pragma unroll
    for (int m = 0; m < 4; m++)
#pragma unroll
      for (int n = 0; n < 4; n++)
        acc[m][n] = __builtin_amdgcn_mfma_f32_16x16x32_bf16(af[m], bfr[n], acc[m][n], 0, 0, 0);
    __syncthreads();
  }
  int gr0 = by * 128 + wrow + (ln >> 4) * 4;
  int gc0 = bx * 128 + wcol + (ln & 15);
#pragma unroll
  for (int m = 0; m < 4; m++)
#pragma unroll
    for (int r = 0; r < 4; r++) {
      size_t grow = (size_t)(gr0 + m * 16 + r);
#pragma unroll
      for (int n = 0; n < 4; n++) {
        int gcol = gc0 + n * 16;
        float v = acc[m][n][r] + (gcol < HH ? bias[gcol] : 0.f);
        C[grow * HHP + gcol] = f2bf(fmaxf(v, 0.f));
      }
    }
}

// GEMM B: cls = relu(h @ W2b^T + b2); accumulate sum(cls^2), sum(cls*x[b]) per row
__global__ __launch_bounds__(256)
void k_gemm_cls(const unsigned short* __restrict__ A, const unsigned short* __restrict__ Bm,
                const float* __restrict__ b2, const float* __restrict__ xf,
                float* __restrict__ dotb, float* __restrict__ nrm2b) {
  const int K = HHP;
  __shared__ short As[128 * 32];
  __shared__ short Bs[128 * 32];
  int tid = threadIdx.x, wv = tid >> 6, ln = tid & 63;
  int bx = blockIdx.x, by = blockIdx.y;
  int wrow = (wv >> 1) * 64, wcol = (wv & 1) * 64;
  f32x4 acc[4][4] = {};
  size_t ar0 = (size_t)by * 128, br0 = (size_t)bx * 128;
  int soff0 = wv * 1024, soff1 = 4096 + wv * 1024;
  int r0 = soff0 >> 6, r1 = soff1 >> 6;
  int rl = ln >> 2;
  int cbyte = (ln & 3) * 16;
  for (int kt = 0; kt < K; kt += 32) {
    const char* gA0 = (const char*)(A + (ar0 + r0 + rl) * K + kt) + cbyte;
    const char* gA1 = (const char*)(A + (ar0 + r1 + rl) * K + kt) + cbyte;
    const char* gB0 = (const char*)(Bm + (br0 + r0 + rl) * K + kt) + cbyte;
    const char* gB1 = (const char*)(Bm + (br0 + r1 + rl) * K + kt) + cbyte;
    gload_lds16(gA0, &As[soff0 >> 1]);
    gload_lds16(gA1, &As[soff1 >> 1]);
    gload_lds16(gB0, &Bs[soff0 >> 1]);
    gload_lds16(gB1, &Bs[soff1 >> 1]);
    __syncthreads();
    bf16x8 af[4], bfr[4];
#pragma unroll
    for (int i = 0; i < 4; i++)
      af[i] = *(const bf16x8*)&As[(wrow + i * 16 + (ln & 15)) * 32 + (ln >> 4) * 8];
#pragma unroll
    for (int i = 0; i < 4; i++)
      bfr[i] = *(const bf16x8*)&Bs[(wcol + i * 16 + (ln & 15)) * 32 + (ln >> 4) * 8];
#pragma unroll
    for (int m = 0; m < 4; m++)
#pragma unroll
      for (int n = 0; n < 4; n++)
        acc[m][n] = __builtin_amdgcn_mfma_f32_16x16x32_bf16(af[m], bfr[n], acc[m][n], 0, 0, 0);
    __syncthreads();
  }
  int gr0 = by * 128 + wrow + (ln >> 4) * 4;
  int gc0 = bx * 128 + wcol + (ln & 15);
#pragma unroll
  for (int m = 0; m < 4; m++)
#pragma unroll
    for (int r = 0; r < 4; r++) {
      int grow = gr0 + m * 16 + r;
      int b = grow / CC;
      const float* xr = xf + (size_t)b * DD;
      float s1 = 0.f, s2 = 0.f;
#pragma unroll
      for (int n = 0; n < 4; n++) {
        int gcol = gc0 + n * 16;
        float cls = fmaxf(acc[m][n][r] + b2[gcol], 0.f);
        s1 += cls * cls;
        s2 += cls * xr[gcol];
      }
      s1 += __shfl_xor(s1, 1, 64); s2 += __shfl_xor(s2, 1, 64);
      s1 += __shfl_xor(s1, 2, 64); s2 += __shfl_xor(s2, 2, 64);
      s1 += __shfl_xor(s1, 4, 64); s2 += __shfl_xor(s2, 4, 64);
      s1 += __shfl_xor(s1, 8, 64); s2 += __shfl_xor(s2, 8, 64);
      if ((ln & 15) == 0) {
        atomicAdd(&nrm2b[grow], s1);
        atomicAdd(&dotb[grow], s2);
      }
    }
}

// ---------------- final: out = scale * (dot / max(||cls||,eps) + bias) ------
__global__ void k_final(const float* __restrict__ dotb, const float* __restrict__ nrm2b,
                        const float* __restrict__ bias_p, const float* __restrict__ scale_cls,
                        float* __restrict__ out) {
  int i = blockIdx.x * 256 + threadIdx.x;
  if (i < MM)
    out[i] = scale_cls[0] * (dotb[i] / fmaxf(sqrtf(nrm2b[i]), 1e-12f) + bias_p[0]);
}

extern "C" void kernel_launch(void* const* d_in, const int* in_sizes, int n_in,
                              void* d_out, int out_size, void* d_ws, size_t ws_size,
                              hipStream_t stream) {
  const float* AttM = (const float*)d_in[0];
  const float* x_in = (const float*)d_in[1];
  const float* Wg = (const float*)d_in[2];
  const float* bg = (const float*)d_in[3];
  const float* W1 = (const float*)d_in[4];
  const float* b1 = (const float*)d_in[5];
  const float* W2 = (const float*)d_in[6];
  const float* b2 = (const float*)d_in[7];
  const float* bias_p = (const float*)d_in[8];
  const float* scale_cls = (const float*)d_in[9];
  float* out = (float*)d_out;

  char* ws = (char*)d_ws;
  size_t off = 0;
  auto alloc = [&](size_t bytes) {
    char* p = ws + off;
    off += (bytes + 255) & ~(size_t)255;
    return p;
  };
  float* xf = (float*)alloc((size_t)BB * DD * 4);
  float* attp = (float*)alloc((size_t)BB * AA * 4);
  unsigned short* comb = (unsigned short*)alloc((size_t)MM * AAP * 2);
  unsigned short* W1b = (unsigned short*)alloc((size_t)HHP * AAP * 2);
  unsigned short* W2b = (unsigned short*)alloc((size_t)DD * HHP * 2);
  unsigned short* hbuf = (unsigned short*)alloc((size_t)MM * HHP * 2);
  float* dotb = (float*)alloc((size_t)MM * 4);
  float* nrm2b = (float*)alloc((size_t)MM * 4);
  (void)ws_size; (void)in_sizes; (void)n_in; (void)out_size;

  // zero the two reduction buffers (contiguous: MM*4 is 256B-aligned)
  hipMemsetAsync(dotb, 0, (size_t)MM * 4 * 2, stream);

  k_norm<<<BB, 256, 0, stream>>>(x_in, xf);
  k_attn<<<BB, 256, 0, stream>>>(xf, Wg, bg, attp);
  k_cast_w1<<<(HHP * AAP + 255) / 256, 256, 0, stream>>>(W1, W1b);
  k_cast_w2<<<(DD * HHP + 255) / 256, 256, 0, stream>>>(W2, W2b);
  k_comb<<<MM, AAP, 0, stream>>>(attp, AttM, comb);
  k_gemm_h<<<dim3(HHP / 128, MM / 128), 256, 0, stream>>>(comb, W1b, b1, hbuf);
  k_gemm_cls<<<dim3(DD / 128, MM / 128), 256, 0, stream>>>(hbuf, W2b, b2, xf, dotb, nrm2b);
  k_final<<<(MM + 255) / 256, 256, 0, stream>>>(dotb, nrm2b, bias_p, scale_cls, out);
}